// Round 8
// baseline (3632.735 us; speedup 1.0000x reference)
//
#include <hip/hip_runtime.h>
#include <hip/hip_bf16.h>

// B=2048, T=80, V=80, E=8, H=256. 2-layer LSTM + dense(last step).
// v3: za-hoisting + full-CU coverage + kk-major ILP streams.
//   lstm1_v2 : 256 blocks x 1024 thr, M=8 rows/block, 16 waves x 16 dims.
//              Per t per wave: 8 kk-steps of {prefetch 4 gate-fragments,
//              4 independent MFMAs}. x-path via 80-entry gate table.
//   za_gemm  : za[t,r,d] = h1[t,r,:] @ W2[h1-half]  (no recurrence ->
//              one-shot GEMM, weights reused across all 163840 rows),
//              stored fp16 gate-packed half4 (i,j,f,o).
//   lstm2_v2 : recurrent part only (K=256 h2 half), za added pre-activation.
// Fallback (ws too small for 320MiB za): R6-proven 128-block lstm2.

#define BB 2048
#define TT 80
#define VV 80
#define HH 256

typedef _Float16 half8 __attribute__((ext_vector_type(8)));
typedef _Float16 half4v __attribute__((ext_vector_type(4)));
typedef float f32x4 __attribute__((ext_vector_type(4)));

__device__ __forceinline__ float sigf(float x) { return 1.0f / (1.0f + __expf(-x)); }
__device__ __forceinline__ float tanhfast(float x) { return 2.0f * sigf(2.0f * x) - 1.0f; }

// LDS h-tile: 16 rows x 512B, XOR-swizzle spreads the 16B column slots.
__device__ __forceinline__ int swz(int row, int kbyte) {
    return row * 512 + (kbyte ^ ((row & 7) << 4));
}

// ---------------- prep ----------------
// tbl[v*256+d] = float4(i, j, f+1, o) layer-1 x-path gate biases.
__global__ void prep_table(const float* __restrict__ emb, const float* __restrict__ W1,
                           const float* __restrict__ b1, float* __restrict__ tbl) {
    int v = blockIdx.x, d = threadIdx.x;
    float4 s;
    s.x = b1[d]; s.y = b1[256 + d]; s.z = b1[512 + d] + 1.0f; s.w = b1[768 + d];
    #pragma unroll
    for (int e = 0; e < 8; ++e) {
        float xv = emb[v * 8 + e];
        const float* wr = W1 + (size_t)e * 1024;
        s.x = fmaf(xv, wr[d], s.x);
        s.y = fmaf(xv, wr[256 + d], s.y);
        s.z = fmaf(xv, wr[512 + d], s.z);
        s.w = fmaf(xv, wr[768 + d], s.w);
    }
    ((float4*)tbl)[v * 256 + d] = s;
}

// v2 stream layout (16 waves x 16 dims): half8 index ((w*8+kk)*4+g)*64 + l
//   col  = g*256 + w*16 + (l&15), krow = base + kk*32 + (l>>4)*8 + e
__global__ void prep_w1_v2(const float* __restrict__ W1, _Float16* __restrict__ Wf) {
    int tid = blockIdx.x * 256 + threadIdx.x;              // 32768
    int l = tid & 63, g = (tid >> 6) & 3, kk = (tid >> 8) & 7, w = (tid >> 11) & 15;
    int col = g * 256 + w * 16 + (l & 15);
    size_t base = ((size_t)((w * 8 + kk) * 4 + g) * 64 + l) * 8;
    #pragma unroll
    for (int e = 0; e < 8; ++e) {
        int krow = 8 + kk * 32 + (l >> 4) * 8 + e;         // skip E rows
        Wf[base + e] = (_Float16)W1[(size_t)krow * 1024 + col];
    }
}
__global__ void prep_w2h_v2(const float* __restrict__ W2, _Float16* __restrict__ Wf) {
    int tid = blockIdx.x * 256 + threadIdx.x;              // 32768
    int l = tid & 63, g = (tid >> 6) & 3, kk = (tid >> 8) & 7, w = (tid >> 11) & 15;
    int col = g * 256 + w * 16 + (l & 15);
    size_t base = ((size_t)((w * 8 + kk) * 4 + g) * 64 + l) * 8;
    #pragma unroll
    for (int e = 0; e < 8; ++e) {
        int krow = 256 + kk * 32 + (l >> 4) * 8 + e;       // h2 half
        Wf[base + e] = (_Float16)W2[(size_t)krow * 1024 + col];
    }
}
__global__ void prep_w2za_v2(const float* __restrict__ W2, _Float16* __restrict__ Wf) {
    int tid = blockIdx.x * 256 + threadIdx.x;              // 32768
    int l = tid & 63, g = (tid >> 6) & 3, kk = (tid >> 8) & 7, w = (tid >> 11) & 15;
    int col = g * 256 + w * 16 + (l & 15);
    size_t base = ((size_t)((w * 8 + kk) * 4 + g) * 64 + l) * 8;
    #pragma unroll
    for (int e = 0; e < 8; ++e) {
        int krow = kk * 32 + (l >> 4) * 8 + e;             // h1 half
        Wf[base + e] = (_Float16)W2[(size_t)krow * 1024 + col];
    }
}

// Old (R6) layout for the fallback lstm2: 8 waves x 32 dims, group-major.
__global__ void prep_w2_old(const float* __restrict__ W2, _Float16* __restrict__ Wf) {
    int tid = blockIdx.x * 256 + threadIdx.x;              // 65536
    int l = tid & 63, kk = (tid >> 6) & 7, j = (tid >> 9) & 1;
    int g = (tid >> 10) & 3, s = (tid >> 12) & 1, w = tid >> 13;
    int col = g * 256 + w * 32 + j * 16 + (l & 15);
    size_t base = ((size_t)((w * 16 + s * 8 + g * 2 + j) * 8 + kk) * 64 + l) * 8;
    #pragma unroll
    for (int e = 0; e < 8; ++e) {
        int krow = (1 - s) * 256 + kk * 32 + (l >> 4) * 8 + e;
        Wf[base + e] = (_Float16)W2[(size_t)krow * 1024 + col];
    }
}

// ---------------- phase 1 ----------------
__global__ __launch_bounds__(1024) void lstm1_v2(
    const int* __restrict__ feats, const float* __restrict__ tbl,
    const _Float16* __restrict__ Wf, _Float16* __restrict__ h1out)
{
    __shared__ char h_lds[8192];
    __shared__ int f_lds[8 * TT];
    const int tid = threadIdx.x, l = tid & 63, w = tid >> 6;
    const int chunk = l >> 4, row_a = l & 15;
    const int dim = w * 16 + (l & 15);
    const int brow = blockIdx.x * 8;

    for (int i = tid; i < 2048; i += 1024) ((float*)h_lds)[i] = 0.f;
    for (int i = tid; i < 8 * TT; i += 1024)
        f_lds[i] = feats[(size_t)(brow + i / TT) * TT + (i % TT)];

    float c[4] = {};
    const float4* tblv = (const float4*)tbl;
    const half8* wp = (const half8*)Wf + (size_t)w * 2048;   // 8kk*4g*64l
    __syncthreads();

    for (int t = 0; t < TT; ++t) {
        half8 a[8];
        #pragma unroll
        for (int kk = 0; kk < 8; ++kk)
            a[kk] = *(const half8*)(h_lds + swz(row_a, kk * 64 + chunk * 16));
        __syncthreads();                     // WAR

        float4 tb[4];
        if (l < 32) {
            #pragma unroll
            for (int m = 0; m < 4; ++m) {
                int f = f_lds[(chunk * 4 + m) * TT + t];
                tb[m] = tblv[f * 256 + dim];
            }
        }

        f32x4 acc[4];
        #pragma unroll
        for (int g = 0; g < 4; ++g) acc[g] = (f32x4){0.f, 0.f, 0.f, 0.f};
        half8 wbuf[2][4];
        #pragma unroll
        for (int g = 0; g < 4; ++g) wbuf[0][g] = wp[g * 64 + l];
        #pragma unroll
        for (int kk = 0; kk < 8; ++kk) {
            const int cur = kk & 1;
            if (kk < 7) {
                #pragma unroll
                for (int g = 0; g < 4; ++g)
                    wbuf[cur ^ 1][g] = wp[(size_t)((kk + 1) * 4 + g) * 64 + l];
            }
            #pragma unroll
            for (int g = 0; g < 4; ++g)      // 4 independent accumulators
                acc[g] = __builtin_amdgcn_mfma_f32_16x16x32_f16(
                    a[kk], wbuf[cur][g], acc[g], 0, 0, 0);
        }

        if (l < 32) {
            #pragma unroll
            for (int m = 0; m < 4; ++m) {
                const int R = chunk * 4 + m;
                float zi = acc[0][m] + tb[m].x, zj = acc[1][m] + tb[m].y;
                float zf = acc[2][m] + tb[m].z, zo = acc[3][m] + tb[m].w;
                c[m] = c[m] * sigf(zf) + sigf(zi) * tanhfast(zj);
                float hv = tanhfast(c[m]) * sigf(zo);
                *(_Float16*)(h_lds + swz(R, dim * 2)) = (_Float16)hv;
                h1out[((size_t)t * BB + brow + R) * HH + dim] = (_Float16)hv;
            }
        }
        __syncthreads();                     // RAW
    }
}

// ---------------- za GEMM: za = h1 @ W2[h1-half], gate-packed fp16 -------
__global__ __launch_bounds__(1024) void za_gemm(
    const _Float16* __restrict__ h1, const _Float16* __restrict__ Wz,
    _Float16* __restrict__ za)
{
    const int tid = threadIdx.x, l = tid & 63, w = tid >> 6;
    const int chunk = l >> 4;
    const int dim = w * 16 + (l & 15);
    const size_t rowbase = (size_t)blockIdx.x * 16;

    half8 a[8];
    #pragma unroll
    for (int kk = 0; kk < 8; ++kk)
        a[kk] = *(const half8*)(h1 + (rowbase + (l & 15)) * HH + kk * 32 + chunk * 8);

    f32x4 acc[4];
    #pragma unroll
    for (int g = 0; g < 4; ++g) acc[g] = (f32x4){0.f, 0.f, 0.f, 0.f};
    const half8* wp = (const half8*)Wz + (size_t)w * 2048;
    half8 wbuf[2][4];
    #pragma unroll
    for (int g = 0; g < 4; ++g) wbuf[0][g] = wp[g * 64 + l];
    #pragma unroll
    for (int kk = 0; kk < 8; ++kk) {
        const int cur = kk & 1;
        if (kk < 7) {
            #pragma unroll
            for (int g = 0; g < 4; ++g)
                wbuf[cur ^ 1][g] = wp[(size_t)((kk + 1) * 4 + g) * 64 + l];
        }
        #pragma unroll
        for (int g = 0; g < 4; ++g)
            acc[g] = __builtin_amdgcn_mfma_f32_16x16x32_f16(
                a[kk], wbuf[cur][g], acc[g], 0, 0, 0);
    }
    #pragma unroll
    for (int m = 0; m < 4; ++m) {
        half4v v = { (_Float16)acc[0][m], (_Float16)acc[1][m],
                     (_Float16)acc[2][m], (_Float16)acc[3][m] };
        *(half4v*)(za + (rowbase + chunk * 4 + m) * 1024 + dim * 4) = v;
    }
}

// ---------------- phase 2 (za path) ----------------
__global__ __launch_bounds__(1024) void lstm2_v2(
    const _Float16* __restrict__ za, const _Float16* __restrict__ Wf,
    const float* __restrict__ b2, const float* __restrict__ Wd,
    const float* __restrict__ bd, float* __restrict__ out)
{
    __shared__ char h_lds[8192];
    const int tid = threadIdx.x, l = tid & 63, w = tid >> 6;
    const int chunk = l >> 4, row_a = l & 15;
    const int dim = w * 16 + (l & 15);
    const int brow = blockIdx.x * 8;

    for (int i = tid; i < 2048; i += 1024) ((float*)h_lds)[i] = 0.f;
    float bv[4];
    #pragma unroll
    for (int g = 0; g < 4; ++g) bv[g] = b2[g * 256 + dim] + (g == 2 ? 1.0f : 0.0f);
    float c[4] = {};
    const half8* wp = (const half8*)Wf + (size_t)w * 2048;
    __syncthreads();

    for (int t = 0; t < TT; ++t) {
        half4v zv[4];
        if (l < 32) {                        // issue early; consumed post-MFMA
            #pragma unroll
            for (int m = 0; m < 4; ++m) {
                const int R = chunk * 4 + m;
                zv[m] = *(const half4v*)(za + ((size_t)t * BB + brow + R) * 1024 + dim * 4);
            }
        }
        half8 a[8];
        #pragma unroll
        for (int kk = 0; kk < 8; ++kk)
            a[kk] = *(const half8*)(h_lds + swz(row_a, kk * 64 + chunk * 16));
        __syncthreads();                     // WAR

        f32x4 acc[4];
        #pragma unroll
        for (int g = 0; g < 4; ++g) acc[g] = (f32x4){0.f, 0.f, 0.f, 0.f};
        half8 wbuf[2][4];
        #pragma unroll
        for (int g = 0; g < 4; ++g) wbuf[0][g] = wp[g * 64 + l];
        #pragma unroll
        for (int kk = 0; kk < 8; ++kk) {
            const int cur = kk & 1;
            if (kk < 7) {
                #pragma unroll
                for (int g = 0; g < 4; ++g)
                    wbuf[cur ^ 1][g] = wp[(size_t)((kk + 1) * 4 + g) * 64 + l];
            }
            #pragma unroll
            for (int g = 0; g < 4; ++g)
                acc[g] = __builtin_amdgcn_mfma_f32_16x16x32_f16(
                    a[kk], wbuf[cur][g], acc[g], 0, 0, 0);
        }

        if (l < 32) {
            #pragma unroll
            for (int m = 0; m < 4; ++m) {
                const int R = chunk * 4 + m;
                float zi = acc[0][m] + bv[0] + (float)zv[m][0];
                float zj = acc[1][m] + bv[1] + (float)zv[m][1];
                float zf = acc[2][m] + bv[2] + (float)zv[m][2];
                float zo = acc[3][m] + bv[3] + (float)zv[m][3];
                c[m] = c[m] * sigf(zf) + sigf(zi) * tanhfast(zj);
                float hv = tanhfast(c[m]) * sigf(zo);
                *(_Float16*)(h_lds + swz(R, dim * 2)) = (_Float16)hv;
            }
        }
        __syncthreads();                     // RAW
    }

    for (int idx = tid; idx < 8 * VV; idx += 1024) {
        int r = idx / VV, v = idx - r * VV;
        float s = bd[v];
        for (int d = 0; d < HH; ++d) {
            float h2 = (float)*(const _Float16*)(h_lds + swz(r, d * 2));
            s = fmaf(h2, Wd[(size_t)d * VV + v], s);
        }
        out[(size_t)(brow + r) * VV + v] = s;
    }
}

// ---------------- phase 2 fallback (R6-proven, 128 blocks, M=16) ---------
__global__ __launch_bounds__(512, 2) void lstm2_old(
    const _Float16* __restrict__ h1, const _Float16* __restrict__ Wf,
    const float* __restrict__ b2, const float* __restrict__ Wd,
    const float* __restrict__ bd, float* __restrict__ out)
{
    __shared__ char h_lds[8192];
    const int tid = threadIdx.x, l = tid & 63, w = tid >> 6;
    const int brow = blockIdx.x * 16;
    const int row_a = l & 15, chunk = l >> 4;
    const int dim0 = w * 32 + (l & 15);

    for (int i = tid; i < 2048; i += 512) ((float*)h_lds)[i] = 0.f;
    float bv[2][4];
    #pragma unroll
    for (int j = 0; j < 2; ++j)
        #pragma unroll
        for (int g = 0; g < 4; ++g)
            bv[j][g] = b2[g * 256 + dim0 + j * 16] + (g == 2 ? 1.0f : 0.0f);
    float c[2][4] = {};
    __syncthreads();

    for (int t = 0; t < TT; ++t) {
        half8 a2[8];
        #pragma unroll
        for (int kk = 0; kk < 8; ++kk)
            a2[kk] = *(const half8*)(h_lds + swz(row_a, kk * 64 + chunk * 16));
        __syncthreads();

        half8 pa[8];
        const _Float16* hp = h1 + ((size_t)t * BB + brow + row_a) * HH + chunk * 8;
        #pragma unroll
        for (int kk = 0; kk < 8; ++kk) pa[kk] = *(const half8*)(hp + kk * 32);

        f32x4 acc[8];
        #pragma unroll
        for (int n = 0; n < 8; ++n) acc[n] = (f32x4){0.f, 0.f, 0.f, 0.f};
        const half8* wp = (const half8*)Wf + (size_t)w * 16 * 512;
        half8 wbuf[2][8];
        #pragma unroll
        for (int kk = 0; kk < 8; ++kk) wbuf[0][kk] = wp[(size_t)kk * 64 + l];
        #pragma unroll
        for (int gid = 0; gid < 16; ++gid) {
            const int cur = gid & 1;
            if (gid < 15) {
                #pragma unroll
                for (int kk = 0; kk < 8; ++kk)
                    wbuf[cur ^ 1][kk] = wp[(size_t)((gid + 1) * 8 + kk) * 64 + l];
            }
            const int s = gid >> 3, acci = gid & 7;
            #pragma unroll
            for (int kk = 0; kk < 8; ++kk)
                acc[acci] = __builtin_amdgcn_mfma_f32_16x16x32_f16(
                    s ? pa[kk] : a2[kk], wbuf[cur][kk], acc[acci], 0, 0, 0);
        }

        #pragma unroll
        for (int j = 0; j < 2; ++j) {
            const int D = dim0 + j * 16;
            #pragma unroll
            for (int m = 0; m < 4; ++m) {
                const int R = chunk * 4 + m;
                float zi = acc[j][m] + bv[j][0];
                float zj = acc[2 + j][m] + bv[j][1];
                float zf = acc[4 + j][m] + bv[j][2];
                float zo = acc[6 + j][m] + bv[j][3];
                c[j][m] = c[j][m] * sigf(zf) + sigf(zi) * tanhfast(zj);
                float hv = tanhfast(c[j][m]) * sigf(zo);
                *(_Float16*)(h_lds + swz(R, D * 2)) = (_Float16)hv;
            }
        }
        __syncthreads();
    }

    for (int idx = tid; idx < 16 * VV; idx += 512) {
        int r = idx / VV, v = idx - r * VV;
        float s = bd[v];
        for (int d = 0; d < HH; ++d) {
            float h2 = (float)*(const _Float16*)(h_lds + swz(r, d * 2));
            s = fmaf(h2, Wd[(size_t)d * VV + v], s);
        }
        out[(size_t)(brow + r) * VV + v] = s;
    }
}

extern "C" void kernel_launch(void* const* d_in, const int* in_sizes, int n_in,
                              void* d_out, int out_size, void* d_ws, size_t ws_size,
                              hipStream_t stream) {
    const int*   feats = (const int*)d_in[0];
    const float* emb   = (const float*)d_in[1];
    const float* W1    = (const float*)d_in[2];
    const float* b1    = (const float*)d_in[3];
    const float* W2    = (const float*)d_in[4];
    const float* b2    = (const float*)d_in[5];
    const float* Wd    = (const float*)d_in[6];
    const float* bd    = (const float*)d_in[7];
    float* out = (float*)d_out;

    char* ws = (char*)d_ws;
    float*    tbl  = (float*)ws;                         // 320 KB
    _Float16* W1f  = (_Float16*)(ws + (512u << 10));     // 512 KB
    _Float16* W2h  = (_Float16*)(ws + (1024u << 10));    // 512 KB (za) / 1 MB old
    _Float16* W2z  = (_Float16*)(ws + (1536u << 10));    // 512 KB (za path only)
    _Float16* h1   = (_Float16*)(ws + (3u << 20));       // 80 MiB
    _Float16* za   = (_Float16*)(ws + (88u << 20));      // 320 MiB

    const bool use_za = ws_size >= (430ull << 20);       // za end ~408 MiB

    prep_table<<<VV, 256, 0, stream>>>(emb, W1, b1, tbl);
    prep_w1_v2<<<128, 256, 0, stream>>>(W1, W1f);
    if (use_za) {
        prep_w2h_v2<<<128, 256, 0, stream>>>(W2, W2h);
        prep_w2za_v2<<<128, 256, 0, stream>>>(W2, W2z);
    } else {
        prep_w2_old<<<256, 256, 0, stream>>>(W2, W2h);   // 1 MB old layout
    }
    lstm1_v2<<<BB / 8, 1024, 0, stream>>>(feats, tbl, W1f, h1);
    if (use_za) {
        za_gemm<<<(BB * TT) / 16, 1024, 0, stream>>>(h1, W2z, za);
        lstm2_v2<<<BB / 8, 1024, 0, stream>>>(za, W2h, b2, Wd, bd, out);
    } else {
        lstm2_old<<<BB / 16, 512, 0, stream>>>(h1, W2h, b2, Wd, bd, out);
    }
}

// Round 9
// 2006.140 us; speedup vs baseline: 1.8108x; 1.8108x over previous
//
#include <hip/hip_runtime.h>
#include <hip/hip_bf16.h>

// B=2048, T=80, V=80, E=8, H=256. 2-layer LSTM + dense(last step).
// v4: M=16/128-block recurrent kernels (min weight traffic), 1 barrier/step
// via double-buffered h-LDS, depth-3 weight prefetch, JIT A-frag rotation,
// chunked za-hoisting (za = h1 @ W2[h1-half] GEMM, T-chunks sized to ws),
// state carried in ws between chunk launches, dense fused into last chunk.

#define BB 2048
#define TT 80
#define VV 80
#define HH 256

typedef _Float16 half8 __attribute__((ext_vector_type(8)));
typedef _Float16 half4v __attribute__((ext_vector_type(4)));
typedef float f32x4 __attribute__((ext_vector_type(4)));

__device__ __forceinline__ float sigf(float x) { return 1.0f / (1.0f + __expf(-x)); }
__device__ __forceinline__ float tanhfast(float x) { return 2.0f * sigf(2.0f * x) - 1.0f; }

// LDS h-tile: 16 rows x 512B, XOR-swizzle spreads the 16B column slots.
__device__ __forceinline__ int swz(int row, int kbyte) {
    return row * 512 + (kbyte ^ ((row & 7) << 4));
}

// ---------------- prep ----------------
__global__ void prep_table(const float* __restrict__ emb, const float* __restrict__ W1,
                           const float* __restrict__ b1, float* __restrict__ tbl) {
    int v = blockIdx.x, d = threadIdx.x;
    float4 s;
    s.x = b1[d]; s.y = b1[256 + d]; s.z = b1[512 + d] + 1.0f; s.w = b1[768 + d];
    #pragma unroll
    for (int e = 0; e < 8; ++e) {
        float xv = emb[v * 8 + e];
        const float* wr = W1 + (size_t)e * 1024;
        s.x = fmaf(xv, wr[d], s.x);
        s.y = fmaf(xv, wr[256 + d], s.y);
        s.z = fmaf(xv, wr[512 + d], s.z);
        s.w = fmaf(xv, wr[768 + d], s.w);
    }
    ((float4*)tbl)[v * 256 + d] = s;
}

// stream layout (16 waves x 16 dims): half8 index ((w*8+kk)*4+g)*64 + l
//   col  = g*256 + w*16 + (l&15), krow = base + kk*32 + (l>>4)*8 + e
__global__ void prep_w1_v2(const float* __restrict__ W1, _Float16* __restrict__ Wf) {
    int tid = blockIdx.x * 256 + threadIdx.x;              // 32768
    int l = tid & 63, g = (tid >> 6) & 3, kk = (tid >> 8) & 7, w = (tid >> 11) & 15;
    int col = g * 256 + w * 16 + (l & 15);
    size_t base = ((size_t)((w * 8 + kk) * 4 + g) * 64 + l) * 8;
    #pragma unroll
    for (int e = 0; e < 8; ++e) {
        int krow = 8 + kk * 32 + (l >> 4) * 8 + e;         // skip E rows
        Wf[base + e] = (_Float16)W1[(size_t)krow * 1024 + col];
    }
}
__global__ void prep_w2h_v2(const float* __restrict__ W2, _Float16* __restrict__ Wf) {
    int tid = blockIdx.x * 256 + threadIdx.x;
    int l = tid & 63, g = (tid >> 6) & 3, kk = (tid >> 8) & 7, w = (tid >> 11) & 15;
    int col = g * 256 + w * 16 + (l & 15);
    size_t base = ((size_t)((w * 8 + kk) * 4 + g) * 64 + l) * 8;
    #pragma unroll
    for (int e = 0; e < 8; ++e) {
        int krow = 256 + kk * 32 + (l >> 4) * 8 + e;       // h2 half
        Wf[base + e] = (_Float16)W2[(size_t)krow * 1024 + col];
    }
}
__global__ void prep_w2za_v2(const float* __restrict__ W2, _Float16* __restrict__ Wf) {
    int tid = blockIdx.x * 256 + threadIdx.x;
    int l = tid & 63, g = (tid >> 6) & 3, kk = (tid >> 8) & 7, w = (tid >> 11) & 15;
    int col = g * 256 + w * 16 + (l & 15);
    size_t base = ((size_t)((w * 8 + kk) * 4 + g) * 64 + l) * 8;
    #pragma unroll
    for (int e = 0; e < 8; ++e) {
        int krow = kk * 32 + (l >> 4) * 8 + e;             // h1 half
        Wf[base + e] = (_Float16)W2[(size_t)krow * 1024 + col];
    }
}
// Old (R6) layout for the fallback lstm2 (1 MiB, K=512 combined).
__global__ void prep_w2_old(const float* __restrict__ W2, _Float16* __restrict__ Wf) {
    int tid = blockIdx.x * 256 + threadIdx.x;              // 65536
    int l = tid & 63, kk = (tid >> 6) & 7, j = (tid >> 9) & 1;
    int g = (tid >> 10) & 3, s = (tid >> 12) & 1, w = tid >> 13;
    int col = g * 256 + w * 32 + j * 16 + (l & 15);
    size_t base = ((size_t)((w * 16 + s * 8 + g * 2 + j) * 8 + kk) * 64 + l) * 8;
    #pragma unroll
    for (int e = 0; e < 8; ++e) {
        int krow = (1 - s) * 256 + kk * 32 + (l >> 4) * 8 + e;
        Wf[base + e] = (_Float16)W2[(size_t)krow * 1024 + col];
    }
}

// ---------------- phase 1: 128 blocks x 1024 thr, M=16 ----------------
__global__ __launch_bounds__(1024) void lstm1_v3(
    const int* __restrict__ feats, const float* __restrict__ tbl,
    const _Float16* __restrict__ Wf, _Float16* __restrict__ h1out)
{
    __shared__ char hb0[8192], hb1[8192];
    __shared__ int f_lds[16 * TT];
    const int tid = threadIdx.x, l = tid & 63, w = tid >> 6;
    const int row_a = l & 15, chunk = l >> 4;
    const int dim = w * 16 + (l & 15);
    const int crow0 = (l >> 4) * 4;
    const int brow = blockIdx.x * 16;

    for (int i = tid; i < 2048; i += 1024) ((float*)hb0)[i] = 0.f;
    for (int i = tid; i < 16 * TT; i += 1024)
        f_lds[i] = feats[(size_t)(brow + i / TT) * TT + (i % TT)];
    float c[4] = {};
    const float4* tblv = (const float4*)tbl;
    const half8* wp = (const half8*)Wf + (size_t)w * 2048;
    __syncthreads();

    for (int t = 0; t < TT; ++t) {
        char* cur = (t & 1) ? hb1 : hb0;
        char* nxt = (t & 1) ? hb0 : hb1;

        float4 tb[4];
        #pragma unroll
        for (int m = 0; m < 4; ++m) {
            int f = f_lds[(crow0 + m) * TT + t];
            tb[m] = tblv[f * 256 + dim];
        }

        f32x4 acc[4];
        #pragma unroll
        for (int g = 0; g < 4; ++g) acc[g] = (f32x4){0.f, 0.f, 0.f, 0.f};

        half8 wbuf[3][4];                        // depth-3 weight prefetch
        #pragma unroll
        for (int p = 0; p < 3; ++p)
            #pragma unroll
            for (int g = 0; g < 4; ++g) wbuf[p][g] = wp[(size_t)(p * 4 + g) * 64 + l];
        half8 aA = *(const half8*)(cur + swz(row_a, 0 * 64 + chunk * 16));
        half8 aB = *(const half8*)(cur + swz(row_a, 1 * 64 + chunk * 16));

        #pragma unroll
        for (int kk = 0; kk < 8; ++kk) {
            half8 av = (kk & 1) ? aB : aA;
            #pragma unroll
            for (int g = 0; g < 4; ++g)
                acc[g] = __builtin_amdgcn_mfma_f32_16x16x32_f16(
                    av, wbuf[kk % 3][g], acc[g], 0, 0, 0);
            if (kk + 2 < 8) {
                half8 an = *(const half8*)(cur + swz(row_a, (kk + 2) * 64 + chunk * 16));
                if (kk & 1) aB = an; else aA = an;
            }
            if (kk + 3 < 8) {
                #pragma unroll
                for (int g = 0; g < 4; ++g)
                    wbuf[(kk + 3) % 3][g] = wp[(size_t)((kk + 3) * 4 + g) * 64 + l];
            }
        }

        #pragma unroll
        for (int m = 0; m < 4; ++m) {
            const int R = crow0 + m;
            float zi = acc[0][m] + tb[m].x, zj = acc[1][m] + tb[m].y;
            float zf = acc[2][m] + tb[m].z, zo = acc[3][m] + tb[m].w;
            c[m] = c[m] * sigf(zf) + sigf(zi) * tanhfast(zj);
            float hv = tanhfast(c[m]) * sigf(zo);
            *(_Float16*)(nxt + swz(R, dim * 2)) = (_Float16)hv;
            h1out[((size_t)t * BB + brow + R) * HH + dim] = (_Float16)hv;
        }
        __syncthreads();                         // single barrier per step
    }
}

// ---------------- za GEMM chunk: za = h1[t0-chunk] @ W2[h1-half] ----------
__global__ __launch_bounds__(1024) void za_gemm_v3(
    const _Float16* __restrict__ h1, const _Float16* __restrict__ Wz,
    _Float16* __restrict__ za, int t0)
{
    const int tid = threadIdx.x, l = tid & 63, w = tid >> 6;
    const int chunk = l >> 4;
    const int dim = w * 16 + (l & 15);
    const size_t rloc = (size_t)blockIdx.x * 16;          // row within chunk
    const size_t rglob = (size_t)t0 * BB + rloc;          // row in h1

    half8 a[8];
    #pragma unroll
    for (int kk = 0; kk < 8; ++kk)
        a[kk] = *(const half8*)(h1 + (rglob + (l & 15)) * HH + kk * 32 + chunk * 8);

    f32x4 acc[4];
    #pragma unroll
    for (int g = 0; g < 4; ++g) acc[g] = (f32x4){0.f, 0.f, 0.f, 0.f};
    const half8* wp = (const half8*)Wz + (size_t)w * 2048;
    half8 wbuf[2][4];
    #pragma unroll
    for (int g = 0; g < 4; ++g) wbuf[0][g] = wp[g * 64 + l];
    #pragma unroll
    for (int kk = 0; kk < 8; ++kk) {
        const int cur = kk & 1;
        if (kk < 7) {
            #pragma unroll
            for (int g = 0; g < 4; ++g)
                wbuf[cur ^ 1][g] = wp[(size_t)((kk + 1) * 4 + g) * 64 + l];
        }
        #pragma unroll
        for (int g = 0; g < 4; ++g)
            acc[g] = __builtin_amdgcn_mfma_f32_16x16x32_f16(
                a[kk], wbuf[cur][g], acc[g], 0, 0, 0);
    }
    #pragma unroll
    for (int m = 0; m < 4; ++m) {
        half4v v = { (_Float16)acc[0][m], (_Float16)acc[1][m],
                     (_Float16)acc[2][m], (_Float16)acc[3][m] };
        *(half4v*)(za + (rloc + chunk * 4 + m) * 1024 + dim * 4) = v;
    }
}

// ------------- phase 2 chunk: 128 blocks x 1024 thr, M=16, K=256 ----------
__global__ __launch_bounds__(1024) void lstm2_v3(
    const _Float16* __restrict__ za, const _Float16* __restrict__ Wf,
    const float* __restrict__ b2, float* __restrict__ c_state,
    _Float16* __restrict__ h_state, const float* __restrict__ Wd,
    const float* __restrict__ bd, float* __restrict__ out,
    int t0, int tc, int last)
{
    __shared__ char hb0[8192], hb1[8192];
    const int tid = threadIdx.x, l = tid & 63, w = tid >> 6;
    const int row_a = l & 15, chunk = l >> 4;
    const int dim = w * 16 + (l & 15);
    const int crow0 = (l >> 4) * 4;
    const int brow = blockIdx.x * 16;

    float bv[4];
    #pragma unroll
    for (int g = 0; g < 4; ++g) bv[g] = b2[g * 256 + dim] + (g == 2 ? 1.0f : 0.0f);

    float c[4];
    if (t0 == 0) {
        for (int i = tid; i < 2048; i += 1024) ((float*)hb0)[i] = 0.f;
        #pragma unroll
        for (int m = 0; m < 4; ++m) c[m] = 0.f;
    } else {
        for (int i = tid; i < 4096; i += 1024) {
            int r = i >> 8, d = i & 255;
            *(_Float16*)(hb0 + swz(r, d * 2)) = h_state[(size_t)(brow + r) * HH + d];
        }
        #pragma unroll
        for (int m = 0; m < 4; ++m)
            c[m] = c_state[(size_t)(brow + crow0 + m) * HH + dim];
    }
    const half8* wp = (const half8*)Wf + (size_t)w * 2048;
    __syncthreads();

    for (int tt = 0; tt < tc; ++tt) {
        char* cur = (tt & 1) ? hb1 : hb0;
        char* nxt = (tt & 1) ? hb0 : hb1;

        half4v zv[4];                            // issue early, consume late
        #pragma unroll
        for (int m = 0; m < 4; ++m)
            zv[m] = *(const half4v*)(za + ((size_t)tt * BB + brow + crow0 + m) * 1024 + dim * 4);

        f32x4 acc[4];
        #pragma unroll
        for (int g = 0; g < 4; ++g) acc[g] = (f32x4){0.f, 0.f, 0.f, 0.f};

        half8 wbuf[3][4];
        #pragma unroll
        for (int p = 0; p < 3; ++p)
            #pragma unroll
            for (int g = 0; g < 4; ++g) wbuf[p][g] = wp[(size_t)(p * 4 + g) * 64 + l];
        half8 aA = *(const half8*)(cur + swz(row_a, 0 * 64 + chunk * 16));
        half8 aB = *(const half8*)(cur + swz(row_a, 1 * 64 + chunk * 16));

        #pragma unroll
        for (int kk = 0; kk < 8; ++kk) {
            half8 av = (kk & 1) ? aB : aA;
            #pragma unroll
            for (int g = 0; g < 4; ++g)
                acc[g] = __builtin_amdgcn_mfma_f32_16x16x32_f16(
                    av, wbuf[kk % 3][g], acc[g], 0, 0, 0);
            if (kk + 2 < 8) {
                half8 an = *(const half8*)(cur + swz(row_a, (kk + 2) * 64 + chunk * 16));
                if (kk & 1) aB = an; else aA = an;
            }
            if (kk + 3 < 8) {
                #pragma unroll
                for (int g = 0; g < 4; ++g)
                    wbuf[(kk + 3) % 3][g] = wp[(size_t)((kk + 3) * 4 + g) * 64 + l];
            }
        }

        #pragma unroll
        for (int m = 0; m < 4; ++m) {
            const int R = crow0 + m;
            float zi = acc[0][m] + bv[0] + (float)zv[m][0];
            float zj = acc[1][m] + bv[1] + (float)zv[m][1];
            float zf = acc[2][m] + bv[2] + (float)zv[m][2];
            float zo = acc[3][m] + bv[3] + (float)zv[m][3];
            c[m] = c[m] * sigf(zf) + sigf(zi) * tanhfast(zj);
            float hv = tanhfast(c[m]) * sigf(zo);
            *(_Float16*)(nxt + swz(R, dim * 2)) = (_Float16)hv;
        }
        __syncthreads();
    }

    char* fin = (tc & 1) ? hb1 : hb0;            // h(t0+tc) lives here
    if (!last) {
        #pragma unroll
        for (int m = 0; m < 4; ++m)
            c_state[(size_t)(brow + crow0 + m) * HH + dim] = c[m];
        for (int i = tid; i < 4096; i += 1024) {
            int r = i >> 8, d = i & 255;
            h_state[(size_t)(brow + r) * HH + d] = *(const _Float16*)(fin + swz(r, d * 2));
        }
    } else {
        for (int idx = tid; idx < 16 * VV; idx += 1024) {
            int r = idx / VV, v = idx - r * VV;
            float s = bd[v];
            for (int d = 0; d < HH; ++d)
                s = fmaf((float)*(const _Float16*)(fin + swz(r, d * 2)),
                         Wd[(size_t)d * VV + v], s);
            out[(size_t)(brow + r) * VV + v] = s;
        }
    }
}

// ---------------- fallback phase 2 (R6-proven, K=512) ----------------
__global__ __launch_bounds__(512, 2) void lstm2_old(
    const _Float16* __restrict__ h1, const _Float16* __restrict__ Wf,
    const float* __restrict__ b2, const float* __restrict__ Wd,
    const float* __restrict__ bd, float* __restrict__ out)
{
    __shared__ char h_lds[8192];
    const int tid = threadIdx.x, l = tid & 63, w = tid >> 6;
    const int brow = blockIdx.x * 16;
    const int row_a = l & 15, chunk = l >> 4;
    const int dim0 = w * 32 + (l & 15);

    for (int i = tid; i < 2048; i += 512) ((float*)h_lds)[i] = 0.f;
    float bv[2][4];
    #pragma unroll
    for (int j = 0; j < 2; ++j)
        #pragma unroll
        for (int g = 0; g < 4; ++g)
            bv[j][g] = b2[g * 256 + dim0 + j * 16] + (g == 2 ? 1.0f : 0.0f);
    float c[2][4] = {};
    __syncthreads();

    for (int t = 0; t < TT; ++t) {
        half8 a2[8];
        #pragma unroll
        for (int kk = 0; kk < 8; ++kk)
            a2[kk] = *(const half8*)(h_lds + swz(row_a, kk * 64 + chunk * 16));
        __syncthreads();

        half8 pa[8];
        const _Float16* hp = h1 + ((size_t)t * BB + brow + row_a) * HH + chunk * 8;
        #pragma unroll
        for (int kk = 0; kk < 8; ++kk) pa[kk] = *(const half8*)(hp + kk * 32);

        f32x4 acc[8];
        #pragma unroll
        for (int n = 0; n < 8; ++n) acc[n] = (f32x4){0.f, 0.f, 0.f, 0.f};
        const half8* wp = (const half8*)Wf + (size_t)w * 16 * 512;
        half8 wbuf[2][8];
        #pragma unroll
        for (int kk = 0; kk < 8; ++kk) wbuf[0][kk] = wp[(size_t)kk * 64 + l];
        #pragma unroll
        for (int gid = 0; gid < 16; ++gid) {
            const int cur = gid & 1;
            if (gid < 15) {
                #pragma unroll
                for (int kk = 0; kk < 8; ++kk)
                    wbuf[cur ^ 1][kk] = wp[(size_t)((gid + 1) * 8 + kk) * 64 + l];
            }
            const int s = gid >> 3, acci = gid & 7;
            #pragma unroll
            for (int kk = 0; kk < 8; ++kk)
                acc[acci] = __builtin_amdgcn_mfma_f32_16x16x32_f16(
                    s ? pa[kk] : a2[kk], wbuf[cur][kk], acc[acci], 0, 0, 0);
        }

        #pragma unroll
        for (int j = 0; j < 2; ++j) {
            const int D = dim0 + j * 16;
            #pragma unroll
            for (int m = 0; m < 4; ++m) {
                const int R = chunk * 4 + m;
                float zi = acc[j][m] + bv[j][0];
                float zj = acc[2 + j][m] + bv[j][1];
                float zf = acc[4 + j][m] + bv[j][2];
                float zo = acc[6 + j][m] + bv[j][3];
                c[j][m] = c[j][m] * sigf(zf) + sigf(zi) * tanhfast(zj);
                float hv = tanhfast(c[j][m]) * sigf(zo);
                *(_Float16*)(h_lds + swz(R, D * 2)) = (_Float16)hv;
            }
        }
        __syncthreads();
    }

    for (int idx = tid; idx < 16 * VV; idx += 512) {
        int r = idx / VV, v = idx - r * VV;
        float s = bd[v];
        for (int d = 0; d < HH; ++d) {
            float h2 = (float)*(const _Float16*)(h_lds + swz(r, d * 2));
            s = fmaf(h2, Wd[(size_t)d * VV + v], s);
        }
        out[(size_t)(brow + r) * VV + v] = s;
    }
}

extern "C" void kernel_launch(void* const* d_in, const int* in_sizes, int n_in,
                              void* d_out, int out_size, void* d_ws, size_t ws_size,
                              hipStream_t stream) {
    const int*   feats = (const int*)d_in[0];
    const float* emb   = (const float*)d_in[1];
    const float* W1    = (const float*)d_in[2];
    const float* b1    = (const float*)d_in[3];
    const float* W2    = (const float*)d_in[4];
    const float* b2    = (const float*)d_in[5];
    const float* Wd    = (const float*)d_in[6];
    const float* bd    = (const float*)d_in[7];
    float* out = (float*)d_out;

    char* ws = (char*)d_ws;
    float*    tbl     = (float*)ws;                       // 320 KiB
    _Float16* W1f     = (_Float16*)(ws + (512u << 10));   // 512 KiB
    _Float16* W2h     = (_Float16*)(ws + (1024u << 10));  // 512 KiB (1 MiB old)
    _Float16* W2z     = (_Float16*)(ws + (1536u << 10));  // 512 KiB
    float*    c_state = (float*)(ws + (2u << 20));        // 2 MiB
    _Float16* h_state = (_Float16*)(ws + (4u << 20));     // 1 MiB
    _Float16* h1      = (_Float16*)(ws + (8u << 20));     // 80 MiB -> ends 88M
    _Float16* za      = (_Float16*)(ws + (88u << 20));    // TC * 4 MiB

    int TC = 0;                                           // za chunk length
    if      (ws_size >= (160ull << 20)) TC = 16;
    else if (ws_size >= (128ull << 20)) TC = 8;
    else if (ws_size >= (108ull << 20)) TC = 4;

    prep_table<<<VV, 256, 0, stream>>>(emb, W1, b1, tbl);
    prep_w1_v2<<<128, 256, 0, stream>>>(W1, W1f);
    lstm1_v3<<<BB / 16, 1024, 0, stream>>>(feats, tbl, W1f, h1);

    if (TC) {
        prep_w2h_v2<<<128, 256, 0, stream>>>(W2, W2h);
        prep_w2za_v2<<<128, 256, 0, stream>>>(W2, W2z);
        for (int t0 = 0; t0 < TT; t0 += TC) {
            za_gemm_v3<<<(BB * TC) / 16, 1024, 0, stream>>>(h1, W2z, za, t0);
            lstm2_v3<<<BB / 16, 1024, 0, stream>>>(za, W2h, b2, c_state, h_state,
                                                   Wd, bd, out, t0, TC,
                                                   (t0 + TC == TT) ? 1 : 0);
        }
    } else {
        prep_w2_old<<<256, 256, 0, stream>>>(W2, W2h);    // uses [1M,2M) = 1 MiB
        lstm2_old<<<BB / 16, 512, 0, stream>>>(h1, W2h, b2, Wd, bd, out);
    }
}